// Round 9
// baseline (95.230 us; speedup 1.0000x reference)
//
#include <hip/hip_runtime.h>
#include <math.h>

#define HEADS 8
#define C 256
#define NUM_STAR 4
#define SLOTS 32              // NUM_STAR * HEADS
#define RSQRT_DH 0.17677669529663688f   // 1/sqrt(32)
#define LN_EPS 1e-5f
#define PF 16                 // partitions per graph (grid = G*PF = 512 = 2/CU)
#define WN 16                 // nodes per wave per round
#define XB2 260               // x_nc row stride (ushorts): q-lanes 2-way-free
#define EP2 40                // e row stride (ushorts); n-extent 32, upper 16 zeroed

#define XNC_W (WN * XB2)      // 4160 ushorts per wave
#define E_W   (SLOTS * EP2)   // 1280 ushorts per wave
#define E_OFF (4 * XNC_W)     // 16640
#define LDS_USH (E_OFF + 4 * E_W)   // 21760 ushorts = 43520 B
#define YLP 260               // Y_lds row stride (floats), 2-way-free

typedef __attribute__((ext_vector_type(8))) short short8;    // bf16x8 MFMA operand
typedef __attribute__((ext_vector_type(4))) float floatx4;   // f32x4 MFMA accum

// f32 -> bf16 (RNE) top-16 (scalar)
__device__ __forceinline__ unsigned int f2b(float f) {
    unsigned int u = __float_as_uint(f);
    return (u + 0x7fffu + ((u >> 16) & 1u)) >> 16;
}
// packed f32x2 -> bf16x2 (RNE): lo -> [15:0], hi -> [31:16]
__device__ __forceinline__ unsigned int pk_bf16(float lo, float hi) {
    unsigned int r;
    asm("v_cvt_pk_bf16_f32 %0, %1, %2" : "=v"(r) : "v"(lo), "v"(hi));
    return r;
}

// ---------------- star prep (+ gstart fold in last block) -------------------
__global__ void k_star_prep(const float* __restrict__ stars,
                            const float* __restrict__ Wq_w, const float* __restrict__ Wq_b,
                            const float* __restrict__ Wk_w, const float* __restrict__ Wk_b,
                            unsigned short* __restrict__ U16, float* __restrict__ eself,
                            float* __restrict__ denom,
                            const int* __restrict__ batch, int N, int G,
                            int* __restrict__ gstart) {
    if (blockIdx.x == gridDim.x - 1) {       // gstart block
        int g = threadIdx.x;
        if (g > G) return;
        if (g == 0) { gstart[0] = 0; return; }
        if (g == G) { gstart[G] = N; return; }
        int lo = 0, hi = N;
        while (lo < hi) {
            int mid = (lo + hi) >> 1;
            if (batch[mid] < g) lo = mid + 1; else hi = mid;
        }
        gstart[g] = lo;
        return;
    }

    __shared__ float xs[C];
    __shared__ float qv[C];
    __shared__ float kv[C];
    const int gs = blockIdx.x;           // g*4 + s
    const int g = gs >> 2, s = gs & 3;
    const int t = threadIdx.x;

    xs[t] = stars[gs * C + t];
    __syncthreads();

    float aq = Wq_b[t], ak = Wk_b[t];
    const float* wq = Wq_w + (size_t)t * C;
    const float* wk = Wk_w + (size_t)t * C;
    #pragma unroll 4
    for (int j = 0; j < C; j += 4) {
        float4 x4 = *(const float4*)(xs + j);
        float4 a4 = *(const float4*)(wq + j);
        aq += a4.x * x4.x + a4.y * x4.y + a4.z * x4.z + a4.w * x4.w;
        float4 b4 = *(const float4*)(wk + j);
        ak += b4.x * x4.x + b4.y * x4.y + b4.z * x4.z + b4.w * x4.w;
    }
    qv[t] = aq; kv[t] = ak;
    __syncthreads();

    {   // self score per head
        float p = qv[t] * kv[t];
        #pragma unroll
        for (int off = 16; off; off >>= 1) p += __shfl_down(p, off, 32);
        if ((t & 31) == 0) {
            int h = t >> 5;
            float e = __expf(p * RSQRT_DH);
            eself[g * SLOTS + s * HEADS + h] = e;
            denom[g * SLOTS + s * HEADS + h] = e;   // init with self term
        }
    }

    // U_t bf16: U16[g][slot=s*8+h][c]
    {
        const int c = t;
        #pragma unroll
        for (int h = 0; h < HEADS; ++h) {
            float u = 0.f;
            #pragma unroll
            for (int d = 0; d < 32; ++d)
                u += Wk_w[(size_t)(h * 32 + d) * C + c] * qv[h * 32 + d];
            U16[((size_t)g * SLOTS + s * HEADS + h) * C + c] =
                (unsigned short)f2b(u * RSQRT_DH);
        }
    }
}

// ---------------- fused MFMA kernel, wave-independent (no hot-loop barriers)
__global__ __launch_bounds__(256, 2)
void k_fused(const float* __restrict__ nodes, const unsigned short* __restrict__ U16,
             const int* __restrict__ gstart, float* __restrict__ denom,
             float* __restrict__ Ypart) {
    __shared__ unsigned short lds[LDS_USH];      // 43,520 B

    const int g = blockIdx.x / PF, pb = blockIdx.x % PF;
    const int t = threadIdx.x;
    const int wv = t >> 6;        // wave 0..3
    const int l  = t & 63;
    const int lr = l & 15;
    const int q  = l >> 4;

    const int glo = gstart[g], ghi = gstart[g + 1];
    const int len = ghi - glo;
    const int Lb = (len + PF - 1) / PF;
    const int blo = glo + pb * Lb;
    const int bhi = min(blo + Lb, ghi);
    const int blen = max(bhi - blo, 0);
    const int wlen = (blen + 3) >> 2;
    const int wlo = blo + wv * wlen;
    const int whi = min(wlo + wlen, bhi);
    const int nrw = (whi > wlo) ? (whi - wlo + WN - 1) / WN : 0;

    unsigned short* xnc = &lds[wv * XNC_W];
    unsigned short* el  = &lds[E_OFF + wv * E_W];

    const floatx4 z4 = {0.f, 0.f, 0.f, 0.f};
    floatx4 yacc[2][16];          // [st][ct]: Y[st*16+q*4+r][ct*16+lr]
    #pragma unroll
    for (int a = 0; a < 2; ++a)
        #pragma unroll
        for (int b = 0; b < 16; ++b) yacc[a][b] = z4;
    float dsum[8];
    #pragma unroll
    for (int i = 0; i < 8; ++i) dsum[i] = 0.f;

    if (nrw > 0) {
        // zero e upper-K (n=16..31) once; wave-private
        {
            const int slot = l >> 1, half = l & 1;
            *(uint4*)&el[slot * EP2 + 16 + half * 8] = make_uint4(0, 0, 0, 0);
        }
        // U_t fragments in registers (both 16-slot tiles)
        short8 ureg[2][8];
        {
            const unsigned short* ug = U16 + (size_t)g * SLOTS * C;
            #pragma unroll
            for (int st2 = 0; st2 < 2; ++st2)
                #pragma unroll
                for (int kt = 0; kt < 8; ++kt)
                    ureg[st2][kt] = *(const short8*)&ug[(st2 * 16 + lr) * C + q * 8 + kt * 32];
        }

        // prefetch round 0: lane l holds channels [4l,4l+4) f32 of each node
        float4 xr[WN];
        {
            #pragma unroll
            for (int i = 0; i < WN; ++i) {
                int gn = wlo + i;
                if (gn >= whi) gn = wlo;          // clamp: real data, e masked to 0
                xr[i] = *(const float4*)&nodes[(size_t)gn * C + l * 4];
            }
        }

        for (int rd = 0; rd < nrw; ++rd) {
            // ---- cvt + write own x rows (bf16, node-major) ----
            #pragma unroll
            for (int i = 0; i < WN; ++i) {
                uint2 w2;
                w2.x = pk_bf16(xr[i].x, xr[i].y);
                w2.y = pk_bf16(xr[i].z, xr[i].w);
                *(uint2*)&xnc[i * XB2 + 4 * l] = w2;
            }
            // ---- prefetch next round (register, wave-private, no barrier) ----
            if (rd + 1 < nrw) {
                #pragma unroll
                for (int i = 0; i < WN; ++i) {
                    int gn = wlo + (rd + 1) * WN + i;
                    if (gn >= whi) gn = wlo;
                    xr[i] = *(const float4*)&nodes[(size_t)gn * C + l * 4];
                }
            }

            // ---- QK^T (B-frag = own x rows, b128; same-wave lgkm dep) ----
            floatx4 s0 = z4, s1 = z4;
            {
                const unsigned short* xrw = &xnc[lr * XB2 + q * 8];
                #pragma unroll
                for (int kt = 0; kt < 8; ++kt) {
                    short8 bx = *(const short8*)(xrw + kt * 32);
                    s0 = __builtin_amdgcn_mfma_f32_16x16x32_bf16(ureg[0][kt], bx, s0, 0, 0, 0);
                    s1 = __builtin_amdgcn_mfma_f32_16x16x32_bf16(ureg[1][kt], bx, s1, 0, 0, 0);
                }
            }

            // ---- exp + mask + denom + e transpose-write ([slot][n]) ----
            {
                const bool valid = (wlo + rd * WN + lr) < whi;
                #pragma unroll
                for (int r = 0; r < 4; ++r) {
                    float e0 = valid ? __expf(s0[r]) : 0.f;
                    float e1 = valid ? __expf(s1[r]) : 0.f;
                    dsum[r]     += e0;
                    dsum[4 + r] += e1;
                    el[(q * 4 + r) * EP2 + lr]        = (unsigned short)f2b(e0);
                    el[(16 + q * 4 + r) * EP2 + lr]   = (unsigned short)f2b(e1);
                }
            }

            // ---- PV: A = e[slot][n] b128 (upper-K zeros), B = x columns ----
            {
                short8 pa0 = *(const short8*)&el[lr * EP2 + q * 8];
                short8 pa1 = *(const short8*)&el[(16 + lr) * EP2 + q * 8];
                #pragma unroll
                for (int ct = 0; ct < 16; ++ct) {
                    short8 bx;
                    if (q < 2) {
                        const unsigned short* col = &xnc[q * 8 * XB2 + ct * 16 + lr];
                        #pragma unroll
                        for (int j = 0; j < 8; ++j) bx[j] = (short)col[j * XB2];
                    } else {
                        #pragma unroll
                        for (int j = 0; j < 8; ++j) bx[j] = 0;
                    }
                    yacc[0][ct] = __builtin_amdgcn_mfma_f32_16x16x32_bf16(pa0, bx, yacc[0][ct], 0, 0, 0);
                    yacc[1][ct] = __builtin_amdgcn_mfma_f32_16x16x32_bf16(pa1, bx, yacc[1][ct], 0, 0, 0);
                }
            }
        }

        // ---- denom: reduce over the 16 node-lanes, atomics from lr==0 ----
        #pragma unroll
        for (int i = 0; i < 8; ++i) {
            float v = dsum[i];
            v += __shfl_xor(v, 1);
            v += __shfl_xor(v, 2);
            v += __shfl_xor(v, 4);
            v += __shfl_xor(v, 8);
            dsum[i] = v;
        }
        if (lr == 0) {
            #pragma unroll
            for (int st2 = 0; st2 < 2; ++st2)
                #pragma unroll
                for (int r = 0; r < 4; ++r)
                    atomicAdd(&denom[g * SLOTS + st2 * 16 + q * 4 + r], dsum[st2 * 4 + r]);
        }
    }

    // ---- combine the 4 waves' yacc via turn-taking LDS reduce ----
    float* Yl = (float*)lds;      // [32][YLP], aliases x_nc region (33,280 B)
    __syncthreads();
    #pragma unroll
    for (int w = 0; w < 4; ++w) {
        if (wv == w) {
            #pragma unroll
            for (int st2 = 0; st2 < 2; ++st2)
                #pragma unroll
                for (int ct = 0; ct < 16; ++ct)
                    #pragma unroll
                    for (int r = 0; r < 4; ++r) {
                        int idx = (st2 * 16 + q * 4 + r) * YLP + ct * 16 + lr;
                        if (w == 0) Yl[idx] = yacc[st2][ct][r];
                        else        Yl[idx] += yacc[st2][ct][r];
                    }
        }
        __syncthreads();
    }
    // ---- write block partial: Ypart[g*PF+pb][slot][c] ----
    {
        float* yg = &Ypart[(((size_t)g * PF + pb) * SLOTS) * C];
        #pragma unroll
        for (int k = 0; k < 8; ++k) {
            int flat = k * 1024 + t * 4;
            int row = flat >> 8, col = flat & 255;
            *(float4*)&yg[flat] = *(const float4*)&Yl[row * YLP + col];
        }
    }
}

// ---------------- epilogue: out = LN(elu(Wv*(Ysum/denom + cself*x) + bv) + stars)
__global__ void k_epilogue(const float* __restrict__ stars,
                           const float* __restrict__ Wv_w, const float* __restrict__ Wv_b,
                           const float* __restrict__ gamma, const float* __restrict__ beta,
                           const float* __restrict__ Ypart, const float* __restrict__ eself,
                           const float* __restrict__ denom, float* __restrict__ out) {
    __shared__ float xs[C];
    __shared__ float yl[HEADS * C];
    __shared__ float cs[HEADS], ivd[HEADS], scl[HEADS];
    __shared__ float rb[8];

    const int gs = blockIdx.x;
    const int g = gs >> 2, s = gs & 3;
    const int t = threadIdx.x;

    xs[t] = stars[gs * C + t];
    if (t < HEADS) {
        float dn = denom[g * SLOTS + s * HEADS + t];
        float iv = 1.f / (dn + 1e-16f);
        ivd[t] = iv;
        cs[t] = eself[g * SLOTS + s * HEADS + t] * iv;
        scl[t] = dn * iv;
    }
    __syncthreads();

    for (int i = t; i < HEADS * C; i += 256) {
        int h = i >> 8, j = i & 255;
        float sum = 0.f;
        #pragma unroll
        for (int pbi = 0; pbi < PF; ++pbi)
            sum += Ypart[(((size_t)g * PF + pbi) * SLOTS + s * HEADS + h) * C + j];
        yl[i] = sum * ivd[h] + cs[h] * xs[j];
    }
    __syncthreads();

    const int c = t, h = c >> 5;
    float a = 0.f;
    const float* wv = Wv_w + (size_t)c * C;
    const float* yh = &yl[h * C];
    #pragma unroll 4
    for (int j = 0; j < C; j += 4) {
        float4 w4 = *(const float4*)(wv + j);
        float4 y4 = *(const float4*)(yh + j);
        a += w4.x * y4.x + w4.y * y4.y + w4.z * y4.z + w4.w * y4.w;
    }
    a += Wv_b[c] * scl[h];

    float v = a > 0.f ? a : (__expf(a) - 1.f);     // ELU
    float r = v + xs[c];                            // residual

    float ssum = r;
    #pragma unroll
    for (int off = 32; off; off >>= 1) ssum += __shfl_down(ssum, off, 64);
    const int wid = t >> 6, lane = t & 63;
    if (lane == 0) rb[wid] = ssum;
    __syncthreads();
    const float mu = (rb[0] + rb[1] + rb[2] + rb[3]) * (1.f / 256.f);
    const float d = r - mu;
    float vsum = d * d;
    #pragma unroll
    for (int off = 32; off; off >>= 1) vsum += __shfl_down(vsum, off, 64);
    if (lane == 0) rb[4 + wid] = vsum;
    __syncthreads();
    const float var = (rb[4] + rb[5] + rb[6] + rb[7]) * (1.f / 256.f);
    out[gs * C + c] = d * rsqrtf(var + LN_EPS) * gamma[c] + beta[c];
}

// ---------------------------------------------------------------------------
extern "C" void kernel_launch(void* const* d_in, const int* in_sizes, int n_in,
                              void* d_out, int out_size, void* d_ws, size_t ws_size,
                              hipStream_t stream) {
    const float* stars = (const float*)d_in[0];
    const float* nodes = (const float*)d_in[1];
    const int*   batch = (const int*)d_in[2];
    const float* Wq_w  = (const float*)d_in[3];
    const float* Wq_b  = (const float*)d_in[4];
    const float* Wk_w  = (const float*)d_in[5];
    const float* Wk_b  = (const float*)d_in[6];
    const float* Wv_w  = (const float*)d_in[7];
    const float* Wv_b  = (const float*)d_in[8];
    const float* gamma = (const float*)d_in[9];
    const float* beta  = (const float*)d_in[10];

    const int N = in_sizes[1] / C;
    const int G = in_sizes[0] / (NUM_STAR * C);

    unsigned short* U16 = (unsigned short*)d_ws;                    // G*SLOTS*C ush
    float* eself = (float*)((char*)d_ws + (size_t)G * SLOTS * C * 2);
    float* denom = eself + (size_t)G * SLOTS;
    float* Ypart = denom + (size_t)G * SLOTS;                       // G*PF*SLOTS*C f32
    int*   gstart = (int*)(Ypart + (size_t)G * PF * SLOTS * C);     // G+1

    float* out = (float*)d_out;

    k_star_prep<<<G * NUM_STAR + 1, 256, 0, stream>>>(stars, Wq_w, Wq_b, Wk_w, Wk_b,
                                                      U16, eself, denom,
                                                      batch, N, G, gstart);
    k_fused<<<G * PF, 256, 0, stream>>>(nodes, U16, gstart, denom, Ypart);
    k_epilogue<<<G * NUM_STAR, 256, 0, stream>>>(stars, Wv_w, Wv_b, gamma, beta,
                                                 Ypart, eself, denom, out);
}

// Round 10
// 68.364 us; speedup vs baseline: 1.3930x; 1.3930x over previous
//
#include <hip/hip_runtime.h>
#include <math.h>

#define HEADS 8
#define C 256
#define NUM_STAR 4
#define SLOTS 32              // NUM_STAR * HEADS
#define RSQRT_DH 0.17677669529663688f   // 1/sqrt(32)
#define LN_EPS 1e-5f
#define PF 16                 // partitions per graph (grid = G*PF = 512 = 2/CU)
#define NT 32                 // nodes per block round
#define FS 260                // fbuf row stride (floats)
#define EP2 40                // e row stride (ushorts)

typedef __attribute__((ext_vector_type(8))) short short8;    // bf16x8 MFMA operand
typedef __attribute__((ext_vector_type(4))) float floatx4;   // f32x4 MFMA accum

typedef const unsigned int __attribute__((address_space(1)))* gp1_t;
typedef unsigned int __attribute__((address_space(3)))* lp3_t;

// f32 -> bf16 (RNE) top-16 (scalar)
__device__ __forceinline__ unsigned int f2b(float f) {
    unsigned int u = __float_as_uint(f);
    return (u + 0x7fffu + ((u >> 16) & 1u)) >> 16;
}
// packed f32x2 -> bf16x2 (RNE): lo -> [15:0], hi -> [31:16]
__device__ __forceinline__ unsigned int pk_bf16(float lo, float hi) {
    unsigned int r;
    asm("v_cvt_pk_bf16_f32 %0, %1, %2" : "=v"(r) : "v"(lo), "v"(hi));
    return r;
}
// async global->LDS, 16B per lane (dest base wave-uniform, + lane*16 implicit)
__device__ __forceinline__ void gld_lds16(const float* g, float* l) {
    __builtin_amdgcn_global_load_lds((gp1_t)(const void*)g, (lp3_t)(void*)l, 16, 0, 0);
}
// raw barrier: LDS-visible, does NOT drain vmcnt
__device__ __forceinline__ void block_sync_lds() {
    asm volatile("s_waitcnt lgkmcnt(0)" ::: "memory");
    __builtin_amdgcn_sched_barrier(0);
    __builtin_amdgcn_s_barrier();
    __builtin_amdgcn_sched_barrier(0);
}

// ---------------- star prep (+ gstart fold in last block) -------------------
__global__ void k_star_prep(const float* __restrict__ stars,
                            const float* __restrict__ Wq_w, const float* __restrict__ Wq_b,
                            const float* __restrict__ Wk_w, const float* __restrict__ Wk_b,
                            unsigned short* __restrict__ U16, float* __restrict__ eself,
                            float* __restrict__ denom,
                            const int* __restrict__ batch, int N, int G,
                            int* __restrict__ gstart) {
    if (blockIdx.x == gridDim.x - 1) {       // gstart block
        int g = threadIdx.x;
        if (g > G) return;
        if (g == 0) { gstart[0] = 0; return; }
        if (g == G) { gstart[G] = N; return; }
        int lo = 0, hi = N;
        while (lo < hi) {
            int mid = (lo + hi) >> 1;
            if (batch[mid] < g) lo = mid + 1; else hi = mid;
        }
        gstart[g] = lo;
        return;
    }

    __shared__ float xs[C];
    __shared__ float qv[C];
    __shared__ float kv[C];
    const int gs = blockIdx.x;           // g*4 + s
    const int g = gs >> 2, s = gs & 3;
    const int t = threadIdx.x;

    xs[t] = stars[gs * C + t];
    __syncthreads();

    float aq = Wq_b[t], ak = Wk_b[t];
    const float* wq = Wq_w + (size_t)t * C;
    const float* wk = Wk_w + (size_t)t * C;
    #pragma unroll 4
    for (int j = 0; j < C; j += 4) {
        float4 x4 = *(const float4*)(xs + j);
        float4 a4 = *(const float4*)(wq + j);
        aq += a4.x * x4.x + a4.y * x4.y + a4.z * x4.z + a4.w * x4.w;
        float4 b4 = *(const float4*)(wk + j);
        ak += b4.x * x4.x + b4.y * x4.y + b4.z * x4.z + b4.w * x4.w;
    }
    qv[t] = aq; kv[t] = ak;
    __syncthreads();

    {   // self score per head
        float p = qv[t] * kv[t];
        #pragma unroll
        for (int off = 16; off; off >>= 1) p += __shfl_down(p, off, 32);
        if ((t & 31) == 0) {
            int h = t >> 5;
            float e = __expf(p * RSQRT_DH);
            eself[g * SLOTS + s * HEADS + h] = e;
            denom[g * SLOTS + s * HEADS + h] = e;   // init with self term
        }
    }

    // U_t bf16: U16[g][slot=s*8+h][c]
    {
        const int c = t;
        #pragma unroll
        for (int h = 0; h < HEADS; ++h) {
            float u = 0.f;
            #pragma unroll
            for (int d = 0; d < 32; ++d)
                u += Wk_w[(size_t)(h * 32 + d) * C + c] * qv[h * 32 + d];
            U16[((size_t)g * SLOTS + s * HEADS + h) * C + c] =
                (unsigned short)f2b(u * RSQRT_DH);
        }
    }
}

// ---------------- fused MFMA kernel: DMA-staged, 32-node rounds -------------
// wave wv: QK^T slot-tile st=wv&1 on node-group ng=wv>>1; PV c-slice wv*64..+64
__global__ __launch_bounds__(256, 2)
void k_fused(const float* __restrict__ nodes, const unsigned short* __restrict__ U16,
             const int* __restrict__ gstart, float* __restrict__ denom,
             float* __restrict__ Ypart) {
    __shared__ float          fbuf[2][NT][FS];   // 66,560 B  f32 [buf][n][c]
    __shared__ unsigned short el[SLOTS * EP2];   //  2,560 B  e [s][n]

    const int g = blockIdx.x / PF, pb = blockIdx.x % PF;
    const int t = threadIdx.x;
    const int wv = t >> 6;        // wave 0..3
    const int l  = t & 63;
    const int lr = l & 15;
    const int q  = l >> 4;
    const int st = wv & 1;        // QK^T slot-tile
    const int ng = wv >> 1;       // QK^T node-group

    const int glo = gstart[g], ghi = gstart[g + 1];
    const int len = ghi - glo;
    const int Lb = (len + PF - 1) / PF;
    const int blo = glo + pb * Lb;
    const int bhi = min(blo + Lb, ghi);
    const int nrw = (bhi > blo) ? (bhi - blo + NT - 1) / NT : 0;

    const floatx4 z4 = {0.f, 0.f, 0.f, 0.f};
    floatx4 yacc[2][4];           // [st2][ct]: Y[st2*16+q*4+r][wv*64+ct*16+lr]
    #pragma unroll
    for (int a = 0; a < 2; ++a)
        #pragma unroll
        for (int b = 0; b < 4; ++b) yacc[a][b] = z4;
    float dsum[4];
    #pragma unroll
    for (int i = 0; i < 4; ++i) dsum[i] = 0.f;

    if (nrw > 0) {
        // ---- U_t fragments for own slot-tile only (32 VGPR) ----
        short8 ureg[8];
        {
            const unsigned short* ug = U16 + (size_t)g * SLOTS * C;
            #pragma unroll
            for (int kt = 0; kt < 8; ++kt)
                ureg[kt] = *(const short8*)&ug[(st * 16 + lr) * C + q * 8 + kt * 32];
        }
        asm volatile("s_waitcnt vmcnt(0)" ::: "memory");   // ureg loads done; clean base

        // DMA-issue round r into fbuf[r&1]: wave stages rows wv*8..wv*8+7
        auto issue = [&](int r) {
            const int buf = r & 1;
            #pragma unroll
            for (int i = 0; i < 8; ++i) {
                int row = wv * 8 + i;
                int gn = blo + r * NT + row;
                if (gn >= bhi) gn = blo;              // clamped dup; e masked to 0
                gld_lds16(nodes + (size_t)gn * C + l * 4, &fbuf[buf][row][0]);
            }
        };

        issue(0);
        issue(1);            // outstanding: 16 per wave

        for (int rd = 0; rd < nrw; ++rd) {
            const int cur = rd & 1;
            asm volatile("s_waitcnt vmcnt(8)" ::: "memory");  // round rd landed (mine)
            __builtin_amdgcn_sched_barrier(0);
            __builtin_amdgcn_s_barrier();                     // everyone's rd landed
            __builtin_amdgcn_sched_barrier(0);

            // ---- QK^T: S[st*16+q*4+r][ng*16+lr] over K=256 ----
            floatx4 sacc = z4;
            {
                const float* xr = &fbuf[cur][ng * 16 + lr][q * 8];
                #pragma unroll
                for (int kt = 0; kt < 8; ++kt) {
                    float4 a4 = *(const float4*)(xr + kt * 32);
                    float4 b4 = *(const float4*)(xr + kt * 32 + 4);
                    short8 bx;
                    ((unsigned int*)&bx)[0] = pk_bf16(a4.x, a4.y);
                    ((unsigned int*)&bx)[1] = pk_bf16(a4.z, a4.w);
                    ((unsigned int*)&bx)[2] = pk_bf16(b4.x, b4.y);
                    ((unsigned int*)&bx)[3] = pk_bf16(b4.z, b4.w);
                    sacc = __builtin_amdgcn_mfma_f32_16x16x32_bf16(ureg[kt], bx, sacc, 0, 0, 0);
                }
            }
            // ---- exp + mask + denom + e write ([slot][n], n = ng*16+lr) ----
            {
                const bool valid = (blo + rd * NT + ng * 16 + lr) < bhi;
                #pragma unroll
                for (int r = 0; r < 4; ++r) {
                    float ev = valid ? __expf(sacc[r]) : 0.f;
                    dsum[r] += ev;
                    el[(st * 16 + q * 4 + r) * EP2 + ng * 16 + lr] = (unsigned short)f2b(ev);
                }
            }
            block_sync_lds();     // e complete; fbuf[cur] still stable

            // ---- PV: Y[s][c] += e[s][n] * x[n][c], K=32 (all real) ----
            {
                short8 pa0 = *(const short8*)&el[lr * EP2 + q * 8];
                short8 pa1 = *(const short8*)&el[(16 + lr) * EP2 + q * 8];
                #pragma unroll
                for (int ct = 0; ct < 4; ++ct) {
                    const int c = wv * 64 + ct * 16 + lr;
                    short8 bx;
                    const float* col = &fbuf[cur][q * 8][c];
                    ((unsigned int*)&bx)[0] = pk_bf16(col[0 * FS], col[1 * FS]);
                    ((unsigned int*)&bx)[1] = pk_bf16(col[2 * FS], col[3 * FS]);
                    ((unsigned int*)&bx)[2] = pk_bf16(col[4 * FS], col[5 * FS]);
                    ((unsigned int*)&bx)[3] = pk_bf16(col[6 * FS], col[7 * FS]);
                    yacc[0][ct] = __builtin_amdgcn_mfma_f32_16x16x32_bf16(pa0, bx, yacc[0][ct], 0, 0, 0);
                    yacc[1][ct] = __builtin_amdgcn_mfma_f32_16x16x32_bf16(pa1, bx, yacc[1][ct], 0, 0, 0);
                }
            }
            block_sync_lds();     // PV done reading fbuf[cur] + el
            issue(rd + 2);        // reuse buffer cur for round rd+2
        }

        asm volatile("s_waitcnt vmcnt(0)" ::: "memory");  // drain trailing DMA pre-exit

        // ---- denom: reduce over 16 node-lanes, atomics from lr==0 ----
        #pragma unroll
        for (int i = 0; i < 4; ++i) {
            float v = dsum[i];
            v += __shfl_xor(v, 1);
            v += __shfl_xor(v, 2);
            v += __shfl_xor(v, 4);
            v += __shfl_xor(v, 8);
            dsum[i] = v;
        }
        if (lr == 0) {
            #pragma unroll
            for (int r = 0; r < 4; ++r)
                atomicAdd(&denom[g * SLOTS + st * 16 + q * 4 + r], dsum[r]);
        }
    }

    // ---- write block partial (waves own disjoint c-slices; zero if nrw==0) --
    {
        float* yg = &Ypart[(((size_t)g * PF + pb) * SLOTS) * C];
        #pragma unroll
        for (int st2 = 0; st2 < 2; ++st2)
            #pragma unroll
            for (int ct = 0; ct < 4; ++ct)
                #pragma unroll
                for (int r = 0; r < 4; ++r)
                    yg[(st2 * 16 + q * 4 + r) * C + wv * 64 + ct * 16 + lr] = yacc[st2][ct][r];
    }
}

// ---------------- epilogue: out = LN(elu(Wv*(Ysum/denom + cself*x) + bv) + stars)
__global__ void k_epilogue(const float* __restrict__ stars,
                           const float* __restrict__ Wv_w, const float* __restrict__ Wv_b,
                           const float* __restrict__ gamma, const float* __restrict__ beta,
                           const float* __restrict__ Ypart, const float* __restrict__ eself,
                           const float* __restrict__ denom, float* __restrict__ out) {
    __shared__ float xs[C];
    __shared__ float yl[HEADS * C];
    __shared__ float cs[HEADS], ivd[HEADS], scl[HEADS];
    __shared__ float rb[8];

    const int gs = blockIdx.x;
    const int g = gs >> 2, s = gs & 3;
    const int t = threadIdx.x;

    xs[t] = stars[gs * C + t];
    if (t < HEADS) {
        float dn = denom[g * SLOTS + s * HEADS + t];
        float iv = 1.f / (dn + 1e-16f);
        ivd[t] = iv;
        cs[t] = eself[g * SLOTS + s * HEADS + t] * iv;
        scl[t] = dn * iv;
    }
    __syncthreads();

    for (int i = t; i < HEADS * C; i += 256) {
        int h = i >> 8, j = i & 255;
        float sum = 0.f;
        #pragma unroll
        for (int pbi = 0; pbi < PF; ++pbi)
            sum += Ypart[(((size_t)g * PF + pbi) * SLOTS + s * HEADS + h) * C + j];
        yl[i] = sum * ivd[h] + cs[h] * xs[j];
    }
    __syncthreads();

    const int c = t, h = c >> 5;
    float a = 0.f;
    const float* wv = Wv_w + (size_t)c * C;
    const float* yh = &yl[h * C];
    #pragma unroll 4
    for (int j = 0; j < C; j += 4) {
        float4 w4 = *(const float4*)(wv + j);
        float4 y4 = *(const float4*)(yh + j);
        a += w4.x * y4.x + w4.y * y4.y + w4.z * y4.z + w4.w * y4.w;
    }
    a += Wv_b[c] * scl[h];

    float v = a > 0.f ? a : (__expf(a) - 1.f);     // ELU
    float r = v + xs[c];                            // residual

    float ssum = r;
    #pragma unroll
    for (int off = 32; off; off >>= 1) ssum += __shfl_down(ssum, off, 64);
    const int wid = t >> 6, lane = t & 63;
    if (lane == 0) rb[wid] = ssum;
    __syncthreads();
    const float mu = (rb[0] + rb[1] + rb[2] + rb[3]) * (1.f / 256.f);
    const float d = r - mu;
    float vsum = d * d;
    #pragma unroll
    for (int off = 32; off; off >>= 1) vsum += __shfl_down(vsum, off, 64);
    if (lane == 0) rb[4 + wid] = vsum;
    __syncthreads();
    const float var = (rb[4] + rb[5] + rb[6] + rb[7]) * (1.f / 256.f);
    out[gs * C + c] = d * rsqrtf(var + LN_EPS) * gamma[c] + beta[c];
}

// ---------------------------------------------------------------------------
extern "C" void kernel_launch(void* const* d_in, const int* in_sizes, int n_in,
                              void* d_out, int out_size, void* d_ws, size_t ws_size,
                              hipStream_t stream) {
    const float* stars = (const float*)d_in[0];
    const float* nodes = (const float*)d_in[1];
    const int*   batch = (const int*)d_in[2];
    const float* Wq_w  = (const float*)d_in[3];
    const float* Wq_b  = (const float*)d_in[4];
    const float* Wk_w  = (const float*)d_in[5];
    const float* Wk_b  = (const float*)d_in[6];
    const float* Wv_w  = (const float*)d_in[7];
    const float* Wv_b  = (const float*)d_in[8];
    const float* gamma = (const float*)d_in[9];
    const float* beta  = (const float*)d_in[10];

    const int N = in_sizes[1] / C;
    const int G = in_sizes[0] / (NUM_STAR * C);

    unsigned short* U16 = (unsigned short*)d_ws;                    // G*SLOTS*C ush
    float* eself = (float*)((char*)d_ws + (size_t)G * SLOTS * C * 2);
    float* denom = eself + (size_t)G * SLOTS;
    float* Ypart = denom + (size_t)G * SLOTS;                       // G*PF*SLOTS*C f32
    int*   gstart = (int*)(Ypart + (size_t)G * PF * SLOTS * C);     // G+1

    float* out = (float*)d_out;

    k_star_prep<<<G * NUM_STAR + 1, 256, 0, stream>>>(stars, Wq_w, Wq_b, Wk_w, Wk_b,
                                                      U16, eself, denom,
                                                      batch, N, G, gstart);
    k_fused<<<G * PF, 256, 0, stream>>>(nodes, U16, gstart, denom, Ypart);
    k_epilogue<<<G * NUM_STAR, 256, 0, stream>>>(stars, Wv_w, Wv_b, gamma, beta,
                                                 Ypart, eself, denom, out);
}